// Round 5
// baseline (233.626 us; speedup 1.0000x reference)
//
#include <hip/hip_runtime.h>
#include <math.h>

#define S_DIM 8
#define N_DIM 2048
#define K_DIM 64
#define APW 4          // atoms per wave (= per 64-thread block)

typedef __attribute__((ext_vector_type(8))) short bf16x8;
typedef __attribute__((ext_vector_type(4))) float f32x4;
typedef __attribute__((ext_vector_type(4))) int   i32x4;

__device__ __forceinline__ unsigned asu(float x) {
    union { float f; unsigned u; } v; v.f = x; return v.u;
}
__device__ __forceinline__ unsigned short f2bf(float x) {
    unsigned u = asu(x);
    return (unsigned short)((u + 0x7FFFu + ((u >> 16) & 1u)) >> 16);
}
// round-nearest-even packed pair (x -> lo16, y -> hi16)
__device__ __forceinline__ unsigned rne_pk(float x, float y) {
    unsigned ux = asu(x), uy = asu(y);
    return ((ux + 0x7FFFu + ((ux >> 16) & 1u)) >> 16) |
           ((uy + 0x7FFFu + ((uy >> 16) & 1u)) & 0xFFFF0000u);
}
// truncation packed pair (cheap; MFMA operand packs on already-rounded data)
__device__ __forceinline__ unsigned trn_pk(float x, float y) {
    return (asu(x) >> 16) | (asu(y) & 0xFFFF0000u);
}
union F8 { i32x4 i; bf16x8 b; };
__device__ __forceinline__ bf16x8 mkfrag(unsigned a, unsigned b, unsigned c, unsigned d) {
    F8 u; u.i = (i32x4){(int)a, (int)b, (int)c, (int)d}; return u.b;
}

// ---------------------------------------------------------------------------
// Prep: packed td table (4 pairs x 16 u32 of bf16-pairs) + bf16 weights.
// (R2 lesson: stage weights to LDS, parallelize — 4-thread version was 103us)
// ---------------------------------------------------------------------------
__global__ __launch_bounds__(256) void prep_kernel(
        const float* __restrict__ ew0, const float* __restrict__ eb0,
        const float* __restrict__ ew1, const float* __restrict__ eb1,
        const float* __restrict__ fw0, const float* __restrict__ fb0,
        const float* __restrict__ fw1, const float* __restrict__ fb1,
        const float* __restrict__ gw0, const float* __restrict__ gw1,
        unsigned* __restrict__ td_pk,
        unsigned short* __restrict__ w0t, unsigned short* __restrict__ w1t) {
    __shared__ float l_ew0[32], l_eb0[16], l_ew1[512], l_eb1[32];
    __shared__ float l_fw0[1024], l_fb0[32], l_fw1[992], l_fb1[31];
    __shared__ float l_h[4][2][16];
    __shared__ float l_tv[4][32];
    __shared__ float l_f1[4][32];
    __shared__ float l_td[4][32];

    const int tid = threadIdx.x;
    if (tid < 32) l_ew0[tid] = ew0[tid];
    if (tid < 16) l_eb0[tid] = eb0[tid];
    for (int i = tid; i < 512; i += 256) l_ew1[i] = ew1[i];
    if (tid < 32) l_eb1[tid] = eb1[tid];
    for (int i = tid; i < 1024; i += 256) l_fw0[i] = fw0[i];
    if (tid < 32) l_fb0[tid] = fb0[tid];
    for (int i = tid; i < 992; i += 256) l_fw1[i] = fw1[i];
    if (tid < 31) l_fb1[tid] = fb1[tid];
    __syncthreads();

    if (tid < 128) {
        const int p = tid >> 5, ord = (tid >> 4) & 1, j = tid & 15;
        const float c = (float)(p >> 1), t = (float)(p & 1);
        const float x0 = ord ? t : c;
        const float x1 = ord ? c : t;
        l_h[p][ord][j] = fmaxf(x0 * l_ew0[j] + x1 * l_ew0[16 + j] + l_eb0[j], 0.f);
    }
    __syncthreads();
    if (tid < 128) {
        const int p = tid >> 5, j = tid & 31;
        float acc = 0.f;
#pragma unroll
        for (int ord = 0; ord < 2; ord++) {
            float v = l_eb1[j];
#pragma unroll
            for (int i = 0; i < 16; i++) v += l_h[p][ord][i] * l_ew1[i * 32 + j];
            acc += fmaxf(v, 0.f);
        }
        l_tv[p][j] = acc;
    }
    __syncthreads();
    if (tid < 128) {
        const int p = tid >> 5, j = tid & 31;
        float v = l_fb0[j];
#pragma unroll
        for (int i = 0; i < 32; i++) v += l_tv[p][i] * l_fw0[i * 32 + j];
        l_f1[p][j] = fmaxf(v, 0.f);
    }
    __syncthreads();
    if (tid < 128) {
        const int p = tid >> 5, j = tid & 31;
        if (j < 31) {
            float v = l_fb1[j];
#pragma unroll
            for (int i = 0; i < 32; i++) v += l_f1[p][i] * l_fw1[i * 31 + j];
            l_td[p][j] = fmaxf(v, 0.f);
        } else {
            l_td[p][31] = 0.f;
        }
    }
    __syncthreads();
    if (tid < 64) {   // td_pk[p*16+i] = bf(td[2i]) | bf(td[2i+1])<<16
        const int p = tid >> 4, i = tid & 15;
        const unsigned lo = f2bf(l_td[p][2 * i]);
        const unsigned hi = (i == 15) ? 0u : (unsigned)f2bf(l_td[p][2 * i + 1]);
        td_pk[tid] = lo | (hi << 16);
    }
    for (int idx = tid; idx < 2048; idx += 256) {   // W0T[j*32+i] = gw0[i][j]
        const int j = idx >> 5, i = idx & 31;
        w0t[idx] = f2bf(gw0[i * 64 + j]);
    }
    for (int idx = tid; idx < 8192; idx += 256) {   // W1T[e*64+j] = gw1[j][e]
        const int e = idx >> 6, j = idx & 63;
        w1t[idx] = f2bf(gw1[j * 128 + e]);
    }
}

// ---------------------------------------------------------------------------
// Main: one wave per block, fully register-resident MFMA chain.
// L1 transposed (M=j): C1 lane layout = (j in regs, k in lanes) which IS the
// A-operand layout for L2's j-contraction (paired 16-chunks -> full K=32).
// st residual via identity-MFMA; g residual h1[k][e&63] via E-matrix MFMA
// transpose (Q). AT via K16-over-k trick (R4-verified). LDS only for rt^T
// (bf16), sel, td table, and the 128x4 A matrix.
// ---------------------------------------------------------------------------
__global__ __launch_bounds__(64, 2) void descr_mfma(
    const float* __restrict__ inputs, const int* __restrict__ input_types,
    const int* __restrict__ neigh_list, const float* __restrict__ length,
    const float* __restrict__ gb0, const float* __restrict__ gb1,
    const unsigned* __restrict__ td_pk, const unsigned short* __restrict__ w0t,
    const unsigned short* __restrict__ w1t, float* __restrict__ out)
{
    __shared__ __align__(16) unsigned short s_rtb[4 * 68];  // rt^T bf16, rows d=0..3
    __shared__ __align__(16) unsigned s_tdpk[80];           // 4 rows + zero row (sel=4)
    __shared__ int s_sel[64];
    __shared__ __align__(16) float s_A[128 * 4];

    const int lane = threadIdx.x;
    const int l = lane & 15;
    const int q = lane >> 4;

    // ---- wave-static fragments ----
    bf16x8 w0f[4];   // A-op of L1T: W0T[jt*16+l][i = q*8+jj]
#pragma unroll
    for (int jt = 0; jt < 4; jt++)
        w0f[jt] = *(const bf16x8*)&w0t[(jt * 16 + l) * 32 + q * 8];

    bf16x8 w1p[8][2];  // B-op of L2, paired j-chunks (jt 2P, 2P+1)
#pragma unroll
    for (int et = 0; et < 8; et++)
#pragma unroll
        for (int P = 0; P < 2; P++) {
            const uint2 a = *(const uint2*)&w1t[(et * 16 + l) * 64 + (2 * P) * 16 + q * 4];
            const uint2 b = *(const uint2*)&w1t[(et * 16 + l) * 64 + (2 * P + 1) * 16 + q * 4];
            w1p[et][P] = mkfrag(a.x, a.y, b.x, b.y);
        }

    // identity A-frags for st residual: idA[p][m=l][i=q*8+jj] = (i == p*16+l)
    bf16x8 idAf[2];
#pragma unroll
    for (int p = 0; p < 2; p++) {
        unsigned d[4];
#pragma unroll
        for (int t = 0; t < 4; t++) {
            const unsigned lo = (q * 8 + 2 * t == p * 16 + l) ? 0x3F80u : 0u;
            const unsigned hi = (q * 8 + 2 * t + 1 == p * 16 + l) ? 0x3F800000u : 0u;
            d[t] = lo | hi;
        }
        idAf[p] = mkfrag(d[0], d[1], d[2], d[3]);
    }
    // E dwords for the Q transpose: ed[t] matches (q*4+2t(+1)) == l
    unsigned ed0, ed1;
    {
        ed0 = ((q * 4 + 0 == l) ? 0x3F80u : 0u) | ((q * 4 + 1 == l) ? 0x3F800000u : 0u);
        ed1 = ((q * 4 + 2 == l) ? 0x3F80u : 0u) | ((q * 4 + 3 == l) ? 0x3F800000u : 0u);
    }
    const bf16x8 ef_even = mkfrag(ed0, ed1, 0, 0);
    const bf16x8 ef_odd  = mkfrag(0, 0, ed0, ed1);

    f32x4 b0v[4];
#pragma unroll
    for (int jt = 0; jt < 4; jt++) b0v[jt] = *(const f32x4*)&gb0[jt * 16 + q * 4];
    float b1f[8];
#pragma unroll
    for (int et = 0; et < 8; et++) b1f[et] = gb1[et * 16 + l];

    s_tdpk[lane] = td_pk[lane];
    if (lane < 16) s_tdpk[64 + lane] = 0u;   // sel=4 (masked) row
    const float Lx = length[0], Ly = length[1], Lz = length[2];
    const float iLx = 1.f / Lx, iLy = 1.f / Ly, iLz = 1.f / Lz;
    const f32x4 zf = {0.f, 0.f, 0.f, 0.f};

    for (int aa = 0; aa < APW; aa++) {
        const int atom = blockIdx.x * APW + aa;
        const int sidx = atom >> 11;

        __syncthreads();   // prev iter LDS reads done (incl. first-iter staging)

        // ---- geometry: lane = neighbor k
        {
            const int nb = neigh_list[atom * K_DIM + lane];
            const bool msk = nb < 0;
            const int idx = msk ? 0 : nb;
            const float cx = inputs[atom * 3 + 0];
            const float cy = inputs[atom * 3 + 1];
            const float cz = inputs[atom * 3 + 2];
            const int nbase = (sidx * N_DIM + idx) * 3;
            float dx = inputs[nbase + 0] - cx;
            float dy = inputs[nbase + 1] - cy;
            float dz = inputs[nbase + 2] - cz;
            dx -= Lx * rintf(dx * iLx);
            dy -= Ly * rintf(dy * iLy);
            dz -= Lz * rintf(dz * iLz);
            const float rsq = dx * dx + dy * dy + dz * dz;
            const float r = sqrtf(rsq > 0.f ? rsq : 1.f);
            const float inv = 1.f / r;
            float sw;
            if (r < 6.f) sw = inv;
            else if (r < 12.f) {
                const float u = (r - 6.f) * (1.f / 6.f);
                sw = inv * (0.5f * __cosf(3.14159265358979323846f * u) + 0.5f);
            } else sw = 0.f;
            const bool valid = (!msk) && (rsq > 0.f);
            const float sij = valid ? sw : 0.f;
            const float f = sij * inv;
            s_rtb[0 * 68 + lane] = f2bf(sij);
            s_rtb[1 * 68 + lane] = f2bf(dx * f);
            s_rtb[2 * 68 + lane] = f2bf(dy * f);
            s_rtb[3 * 68 + lane] = f2bf(dz * f);
            const int ct = input_types[atom];
            const int ntp = input_types[sidx * N_DIM + idx];
            s_sel[lane] = msk ? 4 : (ct * 2 + ntp);
        }
        __syncthreads();

        // ---- st^T B-fragments: B[i=q*8+jj][k-col=l] = st[mt*16+l][i]
        bf16x8 stf[4];
#pragma unroll
        for (int mt = 0; mt < 4; mt++) {
            const int sel = s_sel[mt * 16 + l];
            i32x4 v = *(const i32x4*)&s_tdpk[sel * 16 + q * 4];
            const unsigned sij16 = (unsigned)s_rtb[0 * 68 + mt * 16 + l];
            const int w3 = (q == 3) ? (int)(((unsigned)v.w & 0xFFFFu) | (sij16 << 16)) : v.w;
            F8 u; u.i = (i32x4){v.x, v.y, v.z, w3};
            stf[mt] = u.b;
        }

        // ---- L1 transposed: h1T[j=jt*16+q*4+reg][k=mt*16+l]
        uint2 hpk[4][4];   // [jt][mt] packed bf16 (regs 0..3)
#pragma unroll
        for (int mt = 0; mt < 4; mt++) {
            const f32x4 res0 = __builtin_amdgcn_mfma_f32_16x16x32_bf16(idAf[0], stf[mt], zf, 0, 0, 0);
            const f32x4 res1 = __builtin_amdgcn_mfma_f32_16x16x32_bf16(idAf[1], stf[mt], zf, 0, 0, 0);
#pragma unroll
            for (int jt = 0; jt < 4; jt++) {
                const f32x4 c1 = __builtin_amdgcn_mfma_f32_16x16x32_bf16(w0f[jt], stf[mt], b0v[jt], 0, 0, 0);
                const f32x4& rr = (jt & 1) ? res1 : res0;
                const float h0 = fmaxf(c1[0], 0.f) + rr[0];
                const float h1 = fmaxf(c1[1], 0.f) + rr[1];
                const float h2 = fmaxf(c1[2], 0.f) + rr[2];
                const float h3 = fmaxf(c1[3], 0.f) + rr[3];
                hpk[jt][mt].x = rne_pk(h0, h1);
                hpk[jt][mt].y = rne_pk(h2, h3);
            }
        }

        // ---- L2 + Q transpose + AT accumulation, all register-resident
        f32x4 AT[8] = {zf, zf, zf, zf, zf, zf, zf, zf};
#pragma unroll
        for (int kt = 0; kt < 4; kt++) {
            const bf16x8 af0 = mkfrag(hpk[0][kt].x, hpk[0][kt].y, hpk[1][kt].x, hpk[1][kt].y);
            const bf16x8 af1 = mkfrag(hpk[2][kt].x, hpk[2][kt].y, hpk[3][kt].x, hpk[3][kt].y);
            const uint2 rv = *(const uint2*)&s_rtb[(l & 3) * 68 + kt * 16 + q * 4];
            const bf16x8 rtf = mkfrag(rv.x, rv.y, 0, 0);
            f32x4 Q[4];
            Q[0] = __builtin_amdgcn_mfma_f32_16x16x32_bf16(af0, ef_even, zf, 0, 0, 0);
            Q[1] = __builtin_amdgcn_mfma_f32_16x16x32_bf16(af0, ef_odd,  zf, 0, 0, 0);
            Q[2] = __builtin_amdgcn_mfma_f32_16x16x32_bf16(af1, ef_even, zf, 0, 0, 0);
            Q[3] = __builtin_amdgcn_mfma_f32_16x16x32_bf16(af1, ef_odd,  zf, 0, 0, 0);
#pragma unroll
            for (int et = 0; et < 8; et++) {
                f32x4 c2 = __builtin_amdgcn_mfma_f32_16x16x32_bf16(af0, w1p[et][0], zf, 0, 0, 0);
                c2 = __builtin_amdgcn_mfma_f32_16x16x32_bf16(af1, w1p[et][1], c2, 0, 0, 0);
                const f32x4& qq = Q[et & 3];
                const float g0 = fmaxf(c2[0] + b1f[et], 0.f) + qq[0];
                const float g1 = fmaxf(c2[1] + b1f[et], 0.f) + qq[1];
                const float g2 = fmaxf(c2[2] + b1f[et], 0.f) + qq[2];
                const float g3 = fmaxf(c2[3] + b1f[et], 0.f) + qq[3];
                const bf16x8 gp = mkfrag(trn_pk(g0, g1), trn_pk(g2, g3), 0, 0);
                AT[et] = __builtin_amdgcn_mfma_f32_16x16x32_bf16(rtf, gp, AT[et], 0, 0, 0);
            }
        }

        // ---- A[d][e]: valid rows d=reg live at q==0 lanes
        if (lane < 16) {
#pragma unroll
            for (int et = 0; et < 8; et++)
                *(f32x4*)&s_A[(et * 16 + lane) * 4] = AT[et];
        }
        __syncthreads();

        // ---- D[e][m] = dot(A[:, e], A[:, m]), m<16; coalesced float4 stores
        {
            const int m0 = (lane & 3) * 4;
            const int er = lane >> 2;
            f32x4 Am[4];
#pragma unroll
            for (int t = 0; t < 4; t++) Am[t] = *(const f32x4*)&s_A[(m0 + t) * 4];
            float* op = out + (size_t)atom * 2048;
#pragma unroll
            for (int g = 0; g < 8; g++) {
                const int e = g * 16 + er;
                const f32x4 Ae = *(const f32x4*)&s_A[e * 4];
                f32x4 o;
                o[0] = Ae[0]*Am[0][0] + Ae[1]*Am[0][1] + Ae[2]*Am[0][2] + Ae[3]*Am[0][3];
                o[1] = Ae[0]*Am[1][0] + Ae[1]*Am[1][1] + Ae[2]*Am[1][2] + Ae[3]*Am[1][3];
                o[2] = Ae[0]*Am[2][0] + Ae[1]*Am[2][1] + Ae[2]*Am[2][2] + Ae[3]*Am[2][3];
                o[3] = Ae[0]*Am[3][0] + Ae[1]*Am[3][1] + Ae[2]*Am[3][2] + Ae[3]*Am[3][3];
                *(f32x4*)&op[e * 16 + m0] = o;
            }
        }
    }
}

extern "C" void kernel_launch(void* const* d_in, const int* in_sizes, int n_in,
                              void* d_out, int out_size, void* d_ws, size_t ws_size,
                              hipStream_t stream) {
    (void)in_sizes; (void)n_in; (void)out_size; (void)ws_size;
    const float* inputs      = (const float*)d_in[0];
    const int*   input_types = (const int*)d_in[1];
    const int*   neigh_list  = (const int*)d_in[2];
    const float* length      = (const float*)d_in[3];
    const float* ew0 = (const float*)d_in[4];
    const float* eb0 = (const float*)d_in[5];
    const float* ew1 = (const float*)d_in[6];
    const float* eb1 = (const float*)d_in[7];
    const float* fw0 = (const float*)d_in[8];
    const float* fb0 = (const float*)d_in[9];
    const float* fw1 = (const float*)d_in[10];
    const float* fb1 = (const float*)d_in[11];
    const float* gw0 = (const float*)d_in[12];
    const float* gb0 = (const float*)d_in[13];
    const float* gw1 = (const float*)d_in[14];
    const float* gb1 = (const float*)d_in[15];
    float* out = (float*)d_out;

    unsigned* td_pk = (unsigned*)d_ws;                                 // 64 u32
    unsigned short* w0t = (unsigned short*)((char*)d_ws + 512);        // 2048 bf16
    unsigned short* w1t = (unsigned short*)((char*)d_ws + 512 + 4096); // 8192 bf16

    hipLaunchKernelGGL(prep_kernel, dim3(1), dim3(256), 0, stream,
                       ew0, eb0, ew1, eb1, fw0, fb0, fw1, fb1, gw0, gw1,
                       td_pk, w0t, w1t);

    const int nblocks = (S_DIM * N_DIM) / APW;   // 4096
    hipLaunchKernelGGL(descr_mfma, dim3(nblocks), dim3(64), 0, stream,
                       inputs, input_types, neigh_list, length,
                       gb0, gb1, td_pk, w0t, w1t, out);
}